// Round 5
// baseline (917.496 us; speedup 1.0000x reference)
//
// R12: R11's rowcomb+spfft fusion, but with a HAND-ROLLED device barrier
// (no hipLaunchCooperativeKernel) and device-scope atomic reads of the dot
// slots. R11 post-mortem: plain loads of atomically-written CG scalars after
// grid.sync raced (per-XCD L2 non-coherence / compiler caching) => run-varying
// absmax 0.9-468. Fixes:
//  - arrive: __threadfence + atomicAdd(cnt); spin: __hip_atomic_load ACQUIRE
//    AGENT until cnt >= 512*(itr+1)  (monotone target, no reset race)
//  - replay reads every slot via __hip_atomic_load AGENT
//  - residency guaranteed: 68KB LDS + __launch_bounds__(512,4) => exactly
//    2 blocks/CU, grid 512 = 256 CU x 2; bounded spin-guard => no silent hang
//  Ap stays in registers, p/r read once/iter, 18 dispatches.
#include <hip/hip_runtime.h>
#include <math.h>

#define HW 65536
#define LAM 0.05f

// per-iteration dot slots; rs0 from combine; cnt = barrier arrivals.
struct ScalN {
  double rs0;
  double pap_re[6], pap_im[6], rq_re[6], rq_im[6], qq[6];
  int cnt; int pad;
};

__device__ __forceinline__ float2 cadd(float2 a, float2 b){ return make_float2(a.x+b.x, a.y+b.y); }
__device__ __forceinline__ float2 csub(float2 a, float2 b){ return make_float2(a.x-b.x, a.y-b.y); }
__device__ __forceinline__ float2 cmul(float2 a, float2 b){
  return make_float2(a.x*b.x - a.y*b.y, a.x*b.y + a.y*b.x);
}
__device__ __forceinline__ float2 cmulj(float2 a, float2 b){ // conj(a)*b
  return make_float2(a.x*b.x + a.y*b.y, a.x*b.y - a.y*b.x);
}
__device__ __forceinline__ int swz(int p){ return p ^ (p>>4); }

__device__ __forceinline__ void wave_lds_sync(){
  __builtin_amdgcn_wave_barrier();
  __asm__ __volatile__("s_waitcnt lgkmcnt(0)" ::: "memory");
  __builtin_amdgcn_wave_barrier();
}

template<int S>
__device__ __forceinline__ void bfly4(float2 x0, float2 x1, float2 x2, float2 x3,
                                      float2& y0, float2& y1, float2& y2, float2& y3){
  float2 a  = cadd(x0,x2), bm = csub(x0,x2);
  float2 c  = cadd(x1,x3), d  = csub(x1,x3);
  float2 jd = make_float2(-(float)S*d.y, (float)S*d.x);
  y0 = cadd(a,c); y2 = csub(a,c); y1 = cadd(bm,jd); y3 = csub(bm,jd);
}

// in-register DFT-16, natural order in/out. W16 = e^{S*2pi*i/16}.
template<int S>
__device__ __forceinline__ void dft16(float2* a){
  const float s_ = (float)S;
  const float2 W1 = make_float2( 0.92387953251f,  s_*0.38268343236f);
  const float2 W2 = make_float2( 0.70710678119f,  s_*0.70710678119f);
  const float2 W3 = make_float2( 0.38268343236f,  s_*0.92387953251f);
  const float2 W4_ = make_float2(0.f,              s_*1.f);
  const float2 W6 = make_float2(-0.70710678119f,  s_*0.70710678119f);
  const float2 W9 = make_float2(-0.92387953251f, -s_*0.38268343236f);
  float2 t[16];
#pragma unroll
  for (int n0=0;n0<4;n0++){
    float2 y0,y1,y2,y3;
    bfly4<S>(a[n0], a[n0+4], a[n0+8], a[n0+12], y0,y1,y2,y3);
    if (n0==1){ y1=cmul(y1,W1); y2=cmul(y2,W2); y3=cmul(y3,W3); }
    if (n0==2){ y1=cmul(y1,W2); y2=cmul(y2,W4_); y3=cmul(y3,W6); }
    if (n0==3){ y1=cmul(y1,W3); y2=cmul(y2,W6); y3=cmul(y3,W9); }
    t[n0*4+0]=y0; t[n0*4+1]=y1; t[n0*4+2]=y2; t[n0*4+3]=y3;
  }
#pragma unroll
  for (int k1=0;k1<4;k1++){
    float2 y0,y1,y2,y3;
    bfly4<S>(t[0*4+k1], t[1*4+k1], t[2*4+k1], t[3*4+k1], y0,y1,y2,y3);
    a[k1+0]=y0; a[k1+4]=y1; a[k1+8]=y2; a[k1+12]=y3;
  }
}

// 256-pt FFT, two radix-16 stages, 16 lanes (l) per FFT, swizzled LDS slice.
template<int S>
__device__ void fft256_r16(float2* buf, int l){
  float2 a[16];
#pragma unroll
  for (int j=0;j<16;j++) a[j] = buf[swz(l + 16*j)];
  dft16<S>(a);
  float ang = (float)S * 6.2831853071795865f * (float)l * (1.f/256.f);
  float sn, cs; __sincosf(ang, &sn, &cs);
  float2 wstep = make_float2(cs, sn);
  float2 w = wstep;
#pragma unroll
  for (int k=1;k<16;k++){ a[k] = cmul(a[k], w); w = cmul(w, wstep); }
#pragma unroll
  for (int k=0;k<16;k++) buf[swz(16*k + l)] = a[k];
  wave_lds_sync();
#pragma unroll
  for (int j=0;j<16;j++) a[j] = buf[swz(16*l + j)];
  dft16<S>(a);
  wave_lds_sync();
#pragma unroll
  for (int k=0;k<16;k++) buf[swz(l + 16*k)] = a[k];
  wave_lds_sync();
}

// Compressed W, packed layout per b (9*HW floats):
//   WA float4[HW] = {d0,d1,d2,o01r}; WB float4[HW] = {o01i,o02r,o02i,o12r};
//   WC float [HW] = {o12i};  indexed by wb = v*256+u. Folded 1/65536 norm.
// Also zeroes ScalN (block 0).
__global__ __launch_bounds__(256) void k_w(const float* __restrict__ mask,
                                           const float* __restrict__ tbr,
                                           const float* __restrict__ tbi,
                                           float* __restrict__ Wf,
                                           ScalN* sc){
  if (blockIdx.x==0 && blockIdx.y==0 && threadIdx.x < (int)(sizeof(ScalN)/8)){
    ((double*)sc)[threadIdx.x] = 0.0;
  }
  __shared__ float wtf[9][16][17];
  int tid = threadIdx.x;
  int bx = blockIdx.x;
  int b  = blockIdx.y;
  int u0 = (bx>>4)<<4, v0 = (bx&15)<<4;
  int u_l = tid>>4, v_l = tid&15;
  int pix = (u0+u_l)*256 + (v0+v_l);
  float d0=0,d1=0,d2=0, o01r=0,o01i=0, o02r=0,o02i=0, o12r=0,o12i=0;
#pragma unroll
  for (int t=0;t<12;t++){
    float m = mask[(size_t)(b*12+t)*HW + pix];
    int lb = (b*12+t)*3;
    float l0r = tbr[lb+0], l0i = tbi[lb+0];
    float l1r = tbr[lb+1], l1i = tbi[lb+1];
    float l2r = tbr[lb+2], l2i = tbi[lb+2];
    d0 += m*(l0r*l0r + l0i*l0i);
    d1 += m*(l1r*l1r + l1i*l1i);
    d2 += m*(l2r*l2r + l2i*l2i);
    o01r += m*(l0r*l1r + l0i*l1i); o01i += m*(l0r*l1i - l0i*l1r);
    o02r += m*(l0r*l2r + l0i*l2i); o02i += m*(l0r*l2i - l0i*l2r);
    o12r += m*(l1r*l2r + l1i*l2i); o12i += m*(l1r*l2i - l1i*l2r);
  }
  const float s = 1.0f/65536.0f;
  wtf[0][u_l][v_l] = d0*s;   wtf[1][u_l][v_l] = d1*s;   wtf[2][u_l][v_l] = d2*s;
  wtf[3][u_l][v_l] = o01r*s; wtf[4][u_l][v_l] = o01i*s;
  wtf[5][u_l][v_l] = o02r*s; wtf[6][u_l][v_l] = o02i*s;
  wtf[7][u_l][v_l] = o12r*s; wtf[8][u_l][v_l] = o12i*s;
  __syncthreads();
  int u_l2 = tid&15, v_l2 = tid>>4;
  float* W0 = Wf + (size_t)b*9*HW;
  float4* WA = (float4*)W0;
  float4* WB = (float4*)(W0 + (size_t)4*HW);
  float*  WC = W0 + (size_t)8*HW;
  size_t wb = (size_t)(v0+v_l2)*256 + (u0+u_l2);
  WA[wb] = make_float4(wtf[0][u_l2][v_l2], wtf[1][u_l2][v_l2],
                       wtf[2][u_l2][v_l2], wtf[3][u_l2][v_l2]);
  WB[wb] = make_float4(wtf[4][u_l2][v_l2], wtf[5][u_l2][v_l2],
                       wtf[6][u_l2][v_l2], wtf[7][u_l2][v_l2]);
  WC[wb] = wtf[8][u_l2][v_l2];
}

// Fused setup: bufA rows = row-fft( (1/256) * D * sum_t conj(L_ts) Y[b,t,c] )
// 640 threads: staging thread = (c = tid>>6, px4 = tid&63), float4 Y loads.
__global__ __launch_bounds__(640) void k_yrow(const float* __restrict__ kr,
                                              const float* __restrict__ ki,
                                              const float* __restrict__ tbr,
                                              const float* __restrict__ tbi,
                                              float2* __restrict__ bufA){
  __shared__ float2 lb[30*257];
  int tid = threadIdx.x;
  int r = blockIdx.x, b = blockIdx.y;
  {
    int c = tid>>6, px4 = tid&63;
    float ar[3][4], ai[3][4];
#pragma unroll
    for (int s=0;s<3;s++)
#pragma unroll
      for (int j=0;j<4;j++){ ar[s][j]=0.f; ai[s][j]=0.f; }
#pragma unroll
    for (int t=0;t<12;t++){
      size_t off = ((size_t)((b*12+t)*10+c))*HW + (size_t)r*256 + 4*px4;
      float4 yr4 = *(const float4*)(kr + off);
      float4 yi4 = *(const float4*)(ki + off);
      int lbi = (b*12+t)*3;
      float l0r = tbr[lbi+0], l0i = tbi[lbi+0];
      float l1r = tbr[lbi+1], l1i = tbi[lbi+1];
      float l2r = tbr[lbi+2], l2i = tbi[lbi+2];
      float yrj[4] = {yr4.x, yr4.y, yr4.z, yr4.w};
      float yij[4] = {yi4.x, yi4.y, yi4.z, yi4.w};
#pragma unroll
      for (int j=0;j<4;j++){
        float yr = yrj[j], yi = yij[j];
        ar[0][j] += l0r*yr + l0i*yi;  ai[0][j] += l0r*yi - l0i*yr;
        ar[1][j] += l1r*yr + l1i*yi;  ai[1][j] += l1r*yi - l1i*yr;
        ar[2][j] += l2r*yr + l2i*yi;  ai[2][j] += l2r*yi - l2i*yr;
      }
    }
#pragma unroll
    for (int j=0;j<4;j++){
      int px = 4*px4 + j;
      float sg = (((r ^ px) & 1) ? -1.f : 1.f) * (1.f/256.f);
      int sk = swz(px);
#pragma unroll
      for (int s=0;s<3;s++)
        lb[(c*3+s)*257 + sk] = make_float2(ar[s][j]*sg, ai[s][j]*sg);
    }
  }
  __syncthreads();
  int wv = tid>>6, lane = tid&63, g = lane>>4, l = lane&15;
  int tau = 4*wv + g;
  if (tau < 30){
    float2* lw = &lb[tau*257];
    fft256_r16<-1>(lw, l);
    float2* dst = bufA + (size_t)(b*30+tau)*HW + (size_t)r*256;
#pragma unroll
    for (int j=0;j<8;j++){
      int e = 2*(16*j + l);
      float2 e0 = lw[swz(e)], e1 = lw[swz(e+1)];
      *(float4*)(dst + e) = make_float4(e0.x,e0.y,e1.x,e1.y);
    }
  }
}

// Column pass, in-place. 8 cols/block, 384 threads (24 FFT slots).
// MODE 0: col-fft (-1). MODE 1: col-ifft(+1) + Hermitian W mix + col-fft(-1).
template<int MODE>
__global__ __launch_bounds__(384) void k_colpass(float2* __restrict__ bufA,
                                                 const float* __restrict__ Wf){
  __shared__ float2 lb[24*257];
  int tid = threadIdx.x;
  int wv = tid>>6, lane = tid&63, g = lane>>4, l = lane&15;
  int j0 = blockIdx.x*8;
  int c = blockIdx.y, b = blockIdx.z;
#pragma unroll
  for (int it=0; it<8; it++){
    int idx = it*384 + tid;
    int s = idx>>10, rem = idx&1023, u = rem>>2, cp = rem&3;
    const float2* src = bufA + (size_t)(b*30 + c*3 + s)*HW;
    float4 v = *(const float4*)(src + u*256 + j0 + 2*cp);
    lb[(s*8+2*cp  )*257 + swz(u)] = make_float2(v.x, v.y);
    lb[(s*8+2*cp+1)*257 + swz(u)] = make_float2(v.z, v.w);
  }
  __syncthreads();
  int tau = 4*wv + g;
  if (MODE==0){
    fft256_r16<-1>(&lb[tau*257], l);
  } else {
    fft256_r16<1>(&lb[tau*257], l);
    __syncthreads();
    const float* W0 = Wf + (size_t)b*9*HW;
    const float4* WA = (const float4*)W0;
    const float4* WB = (const float4*)(W0 + (size_t)4*HW);
    const float*  WC = W0 + (size_t)8*HW;
    for (int idx=tid; idx<2048; idx+=384){
      int u = idx&255, col = idx>>8;
      int su = swz(u);
      int v = j0 + col;
      float2 x0 = lb[(0*8+col)*257 + su];
      float2 x1 = lb[(1*8+col)*257 + su];
      float2 x2 = lb[(2*8+col)*257 + su];
      size_t wb = (size_t)v*256 + u;
      float4 wa = WA[wb];
      float4 wbv = WB[wb];
      float d0 = wa.x, d1 = wa.y, d2 = wa.z, o01r = wa.w;
      float o01i = wbv.x, o02r = wbv.y, o02i = wbv.z, o12r = wbv.w;
      float o12i = WC[wb];
      float2 y0, y1, y2;
      y0.x = d0*x0.x + o01r*x1.x - o01i*x1.y + o02r*x2.x - o02i*x2.y;
      y0.y = d0*x0.y + o01r*x1.y + o01i*x1.x + o02r*x2.y + o02i*x2.x;
      y1.x = o01r*x0.x + o01i*x0.y + d1*x1.x + o12r*x2.x - o12i*x2.y;
      y1.y = o01r*x0.y - o01i*x0.x + d1*x1.y + o12r*x2.y + o12i*x2.x;
      y2.x = o02r*x0.x + o02i*x0.y + o12r*x1.x + o12i*x1.y + d2*x2.x;
      y2.y = o02r*x0.y - o02i*x0.x + o12r*x1.y - o12i*x1.x + d2*x2.y;
      lb[(0*8+col)*257 + su] = y0;
      lb[(1*8+col)*257 + su] = y1;
      lb[(2*8+col)*257 + su] = y2;
    }
    __syncthreads();
    fft256_r16<-1>(&lb[tau*257], l);
  }
  __syncthreads();
#pragma unroll
  for (int it=0; it<8; it++){
    int idx = it*384 + tid;
    int s = idx>>10, rem = idx&1023, u = rem>>2, cp = rem&3;
    float2* dst = bufA + (size_t)(b*30 + c*3 + s)*HW;
    float2 e0 = lb[(s*8+2*cp  )*257 + swz(u)];
    float2 e1 = lb[(s*8+2*cp+1)*257 + swz(u)];
    *(float4*)(dst + u*256 + j0 + 2*cp) = make_float4(e0.x, e0.y, e1.x, e1.y);
  }
}

// Setup combine: b = sum_c conj(S_c) bufA + lambda*D*MO; z=0, r=p=b;
// rs0 += |b|^2 (atomic).
__global__ __launch_bounds__(256) void k_combine(const float2* __restrict__ bufA,
                                                 const float* __restrict__ sr_,
                                                 const float* __restrict__ si_,
                                                 const float* __restrict__ mor,
                                                 const float* __restrict__ moi,
                                                 float2* __restrict__ z,
                                                 float2* __restrict__ r,
                                                 float2* __restrict__ p,
                                                 ScalN* sc){
  __shared__ double sd[4];
  int tid = threadIdx.x;
  int i = blockIdx.x*256 + tid;          // [0, 6*HW)
  int pix = i & (HW-1);
  int bs = i >> 16;
  int b = bs/3, s = bs - 3*b;
  float2 acc = make_float2(0.f, 0.f);
#pragma unroll
  for (int c=0;c<10;c++){
    float2 F  = bufA[(size_t)(b*30 + c*3 + s)*HW + pix];
    size_t so = (size_t)(b*10+c)*HW + pix;
    float2 sv = make_float2(sr_[so], si_[so]);
    acc = cadd(acc, cmulj(sv, F));
  }
  float sgl = (((pix>>8)^pix)&1 ? -1.f : 1.f) * LAM;
  acc.x += sgl*mor[i]; acc.y += sgl*moi[i];
  z[i] = make_float2(0.f,0.f);
  r[i] = acc; p[i] = acc;
  double dre = (double)acc.x*acc.x + (double)acc.y*acc.y;
  for (int off=32; off>0; off>>=1) dre += __shfl_down(dre, off, 64);
  if ((tid&63)==0) sd[tid>>6] = dre;
  __syncthreads();
  if (tid==0) atomicAdd(&sc->rs0, sd[0]+sd[1]+sd[2]+sd[3]);
}

// First S*p + row-ifft (no CG update pending). Block = (row r, b), 512 thr.
__global__ __launch_bounds__(512) void k_sp0(const float2* __restrict__ p,
                                             const float* __restrict__ sr_,
                                             const float* __restrict__ si_,
                                             float2* __restrict__ bufA){
  __shared__ float2 lb[30*257];
  __shared__ float2 pbuf[3][256];
  int tid = threadIdx.x;
  int wv = tid>>6, lane = tid&63, g = lane>>4, l = lane&15;
  int r = blockIdx.x, b = blockIdx.y;
  for (int i = tid; i < 768; i += 512){
    int s = i>>8, px = i&255;
    pbuf[s][px] = p[(size_t)(b*3+s)*HW + (size_t)r*256 + px];
  }
  __syncthreads();
  {
    int px = tid & 255, h = tid >> 8, sk = swz(px);
    float2 pv0 = pbuf[0][px], pv1 = pbuf[1][px], pv2 = pbuf[2][px];
#pragma unroll
    for (int k=0;k<5;k++){
      int c = h + 2*k;
      size_t so = (size_t)(b*10+c)*HW + (size_t)r*256 + px;
      float2 sv = make_float2(sr_[so], si_[so]);
      lb[(c*3+0)*257 + sk] = cmul(sv, pv0);
      lb[(c*3+1)*257 + sk] = cmul(sv, pv1);
      lb[(c*3+2)*257 + sk] = cmul(sv, pv2);
    }
  }
  __syncthreads();
  int tau = 4*wv + g;
  if (tau < 30){
    float2* lw = &lb[tau*257];
    fft256_r16<1>(lw, l);
    float2* dst = bufA + (size_t)(b*30+tau)*HW + (size_t)r*256;
#pragma unroll
    for (int j=0;j<8;j++){
      int e = 2*(16*j + l);
      float2 e0 = lw[swz(e)], e1 = lw[swz(e+1)];
      *(float4*)(dst + e) = make_float4(e0.x,e0.y,e1.x,e1.y);
    }
  }
}

// Fused kernel with HAND-ROLLED grid barrier: row-fft + conj(S) combine +
// LAM*p (Ap in regs) + dot slots -> device barrier -> scalar replay (atomic
// slot reads) -> CG update -> S*p + row-ifft.
// Residency: 68KB LDS + launch_bounds(512,4) => exactly 2 blocks/CU;
// grid (256,2) = 512 blocks = 256 CUs x 2 co-resident (barrier is safe).
__global__ __launch_bounds__(512,4) void k_rowspfft(float2* __restrict__ bufA,
                                                    const float* __restrict__ sr_,
                                                    const float* __restrict__ si_,
                                                    float2* __restrict__ pvec,
                                                    float2* __restrict__ rvec,
                                                    float2* __restrict__ zvec,
                                                    ScalN* sc,
                                                    int itr, int last){
  __shared__ float2 lb[30*257];
  __shared__ float2 pb[3][256];     // part (phase1) then pbuf (phase2)
  __shared__ double sd[5][4];
  __shared__ float sca[4];
  int tid = threadIdx.x;
  int wv = tid>>6, lane = tid&63, g = lane>>4, l = lane&15;
  int r = blockIdx.x, b = blockIdx.y;
  int tau = 4*wv + g;
  // ---- phase 1: row-fft of bufA row ----
  if (tau < 30){
    const float2* src = bufA + (size_t)(b*30+tau)*HW + (size_t)r*256;
    float2* lw = &lb[tau*257];
#pragma unroll
    for (int j=0;j<8;j++){
      int e = 2*(16*j + l);
      float4 v = *(const float4*)(src + e);
      lw[swz(e)]   = make_float2(v.x, v.y);
      lw[swz(e+1)] = make_float2(v.z, v.w);
    }
    wave_lds_sync();
    fft256_r16<-1>(lw, l);
  }
  __syncthreads();
  // ---- conj(S) combine, two c-halves over all 512 threads ----
  int px = tid & 255, h = tid >> 8, sk = swz(px);
  float2 a0={0,0}, a1={0,0}, a2={0,0};
#pragma unroll
  for (int k=0;k<5;k++){
    int c = h + 2*k;
    size_t so = (size_t)(b*10+c)*HW + (size_t)r*256 + px;
    float2 sv = make_float2(sr_[so], si_[so]);
    a0 = cadd(a0, cmulj(sv, lb[(c*3+0)*257 + sk]));
    a1 = cadd(a1, cmulj(sv, lb[(c*3+1)*257 + sk]));
    a2 = cadd(a2, cmulj(sv, lb[(c*3+2)*257 + sk]));
  }
  if (h==1){ pb[0][px]=a0; pb[1][px]=a1; pb[2][px]=a2; }
  __syncthreads();
  float2 pv[3], rv[3], ap3[3];
  double d0=0.0, d1=0.0, d2=0.0, d3=0.0, d4=0.0;
  if (tid < 256){
    a0 = cadd(a0, pb[0][px]);
    a1 = cadd(a1, pb[1][px]);
    a2 = cadd(a2, pb[2][px]);
    float2 accs[3] = {a0,a1,a2};
#pragma unroll
    for (int s=0;s<3;s++){
      size_t oi = (size_t)(b*3+s)*HW + (size_t)r*256 + px;
      float2 acc = accs[s];
      float2 av = pvec[oi];
      float2 rvv = rvec[oi];
      acc.x += LAM*av.x; acc.y += LAM*av.y;
      pv[s] = av; rv[s] = rvv; ap3[s] = acc;
      d0 += (double)av.x*acc.x + (double)av.y*acc.y;    // pap
      d1 += (double)av.x*acc.y - (double)av.y*acc.x;
      d2 += (double)rvv.x*acc.x + (double)rvv.y*acc.y;  // rq
      d3 += (double)rvv.x*acc.y - (double)rvv.y*acc.x;
      d4 += (double)acc.x*acc.x + (double)acc.y*acc.y;  // qq
    }
  }
  for (int off=32; off>0; off>>=1){
    d0 += __shfl_down(d0, off, 64);
    d1 += __shfl_down(d1, off, 64);
    d2 += __shfl_down(d2, off, 64);
    d3 += __shfl_down(d3, off, 64);
    d4 += __shfl_down(d4, off, 64);
  }
  if (lane==0 && wv<4){ sd[0][wv]=d0; sd[1][wv]=d1; sd[2][wv]=d2; sd[3][wv]=d3; sd[4][wv]=d4; }
  __syncthreads();
  // ---- arrive + spin barrier + replay (tid 0 only), broadcast via sca ----
  if (tid==0){
    double t0=0,t1=0,t2=0,t3=0,t4=0;
#pragma unroll
    for (int q=0;q<4;q++){ t0+=sd[0][q]; t1+=sd[1][q]; t2+=sd[2][q]; t3+=sd[3][q]; t4+=sd[4][q]; }
    atomicAdd(&sc->pap_re[itr], t0); atomicAdd(&sc->pap_im[itr], t1);
    atomicAdd(&sc->rq_re[itr],  t2); atomicAdd(&sc->rq_im[itr],  t3);
    atomicAdd(&sc->qq[itr],     t4);
    __threadfence();
    atomicAdd(&sc->cnt, 1);
    int target = (int)(gridDim.x*gridDim.y) * (itr+1);
    long guard = 0;
    while (__hip_atomic_load(&sc->cnt, __ATOMIC_ACQUIRE, __HIP_MEMORY_SCOPE_AGENT) < target){
      __builtin_amdgcn_s_sleep(2);
      if (++guard > (1L<<22)) break;   // fail loud (wrong result), never hang
    }
    // scalar replay: deterministic, identical in every block; atomic reads
    double rs = __hip_atomic_load(&sc->rs0, __ATOMIC_RELAXED, __HIP_MEMORY_SCOPE_AGENT);
    double alr=0.0, ali=0.0, beta=0.0;
    int done = 0, applied = 0;
    for (int j=0; j<=itr; ++j){
      if (!done){
        double pr = __hip_atomic_load(&sc->pap_re[j], __ATOMIC_RELAXED, __HIP_MEMORY_SCOPE_AGENT) + 1e-20;
        double pi = __hip_atomic_load(&sc->pap_im[j], __ATOMIC_RELAXED, __HIP_MEMORY_SCOPE_AGENT);
        double rqr= __hip_atomic_load(&sc->rq_re[j],  __ATOMIC_RELAXED, __HIP_MEMORY_SCOPE_AGENT);
        double rqi= __hip_atomic_load(&sc->rq_im[j],  __ATOMIC_RELAXED, __HIP_MEMORY_SCOPE_AGENT);
        double qq = __hip_atomic_load(&sc->qq[j],     __ATOMIC_RELAXED, __HIP_MEMORY_SCOPE_AGENT);
        double den = pr*pr + pi*pi;
        alr =  rs*pr/den; ali = -rs*pi/den;
        double rs_new = rs - 2.0*(alr*rqr - ali*rqi) + (alr*alr + ali*ali)*qq;
        beta = rs_new/(rs + 1e-20);
        rs = rs_new;
        applied = 1;
        if (fabs(rs) < 1e-10) done = 1;
      } else {
        applied = 0;
      }
    }
    sca[0]=(float)alr; sca[1]=(float)ali; sca[2]=(float)beta; sca[3]=(float)applied;
  }
  __syncthreads();
  float2 alpha = make_float2(sca[0], sca[1]);
  float beta = sca[2];
  int applied = sca[3] != 0.f;
  // ---- CG vector update (eager, exact) ----
  if (tid < 256 && applied){
#pragma unroll
    for (int s=0;s<3;s++){
      size_t oi = (size_t)(b*3+s)*HW + (size_t)r*256 + px;
      float2 zv = zvec[oi];
      zv = cadd(zv, cmul(alpha, pv[s]));
      zvec[oi] = zv;
      float2 rn = csub(rv[s], cmul(alpha, ap3[s]));
      rvec[oi] = rn;
      float2 pn = make_float2(rn.x + beta*pv[s].x, rn.y + beta*pv[s].y);
      pvec[oi] = pn;
      pv[s] = pn;
    }
  }
  if (last) return;
  // ---- S*p + row-ifft for next iteration ----
  if (tid < 256){ pb[0][px]=pv[0]; pb[1][px]=pv[1]; pb[2][px]=pv[2]; }
  __syncthreads();
  {
    float2 pv0 = pb[0][px], pv1 = pb[1][px], pv2 = pb[2][px];
#pragma unroll
    for (int k=0;k<5;k++){
      int c = h + 2*k;
      size_t so = (size_t)(b*10+c)*HW + (size_t)r*256 + px;
      float2 sv = make_float2(sr_[so], si_[so]);
      lb[(c*3+0)*257 + sk] = cmul(sv, pv0);
      lb[(c*3+1)*257 + sk] = cmul(sv, pv1);
      lb[(c*3+2)*257 + sk] = cmul(sv, pv2);
    }
  }
  __syncthreads();
  if (tau < 30){
    float2* lw = &lb[tau*257];
    fft256_r16<1>(lw, l);
    float2* dst = bufA + (size_t)(b*30+tau)*HW + (size_t)r*256;
#pragma unroll
    for (int j=0;j<8;j++){
      int e = 2*(16*j + l);
      float2 e0 = lw[swz(e)], e1 = lw[swz(e+1)];
      *(float4*)(dst + e) = make_float4(e0.x,e0.y,e1.x,e1.y);
    }
  }
}

// Output: un-tilde (D), interleave re/im. z is fully updated.
__global__ __launch_bounds__(256) void k_out(const float2* __restrict__ z,
                                             float* __restrict__ out){
  int i = blockIdx.x*256 + threadIdx.x;
  int pix = i & (HW-1);
  float sgn = (((pix>>8)^pix)&1) ? -1.f : 1.f;
  float2 zv = z[i];
  out[2*i]   = sgn*zv.x;
  out[2*i+1] = sgn*zv.y;
}

extern "C" void kernel_launch(void* const* d_in, const int* in_sizes, int n_in,
                              void* d_out, int out_size, void* d_ws, size_t ws_size,
                              hipStream_t stream){
  const float* kr   = (const float*)d_in[0];
  const float* ki   = (const float*)d_in[1];
  const float* mor  = (const float*)d_in[2];
  const float* moi  = (const float*)d_in[3];
  const float* sr   = (const float*)d_in[4];
  const float* si   = (const float*)d_in[5];
  const float* tbr  = (const float*)d_in[6];
  const float* tbi  = (const float*)d_in[7];
  const float* mask = (const float*)d_in[8];
  float* out = (float*)d_out;

  float2* ws   = (float2*)d_ws;
  float2* bufA = ws;                       // 60*HW float2
  float*  Wf   = (float*)(ws + 3932160);   // 18*HW floats (9*HW per b, packed)
  float2* z    = ws + 4521984;             // 6*HW each
  float2* r    = ws + 4915200;
  float2* p    = ws + 5308416;
  ScalN*  sc   = (ScalN*)(ws + 6094848);

  k_w<<<dim3(256,2),dim3(256),0,stream>>>(mask, tbr, tbi, Wf, sc);
  k_yrow<<<dim3(256,2),dim3(640),0,stream>>>(kr, ki, tbr, tbi, bufA);
  k_colpass<0><<<dim3(32,10,2),dim3(384),0,stream>>>(bufA, Wf);
  k_combine<<<dim3(1536),dim3(256),0,stream>>>(bufA, sr, si, mor, moi,
                                               z, r, p, sc);
  k_sp0<<<dim3(256,2),dim3(512),0,stream>>>(p, sr, si, bufA);
  for (int it=0; it<6; ++it){
    k_colpass<1><<<dim3(32,10,2),dim3(384),0,stream>>>(bufA, Wf);
    k_rowspfft<<<dim3(256,2),dim3(512),0,stream>>>(bufA, sr, si, p, r, z,
                                                   sc, it, it==5 ? 1 : 0);
  }
  k_out<<<dim3(1536),dim3(256),0,stream>>>(z, out);
}

// Round 6
// 718.333 us; speedup vs baseline: 1.2773x; 1.2773x over previous
//
// R13: revert to R10 structure (722us verified; R12's in-kernel grid barrier
// cost ~34us/iter — kernel-boundary sync is cheaper, branch abandoned).
// Two deltas on top of R10:
//  1. k_bsp = k_combine + first k_spfft fused (row-block): saves 1 dispatch +
//     p round-trip; loop runs spfft only for it>=1.
//  2. T14 load hoisting: S (and p/r) loads issued at kernel top in
//     spfft/rowcomb/k_bsp, consumed after FFT phases (latency hides under LDS
//     work instead of serializing after __syncthreads).
// k_yrow kept as-is: it reads 251MB of Y via L3 (~4.3TB/s) — at its floor.
#include <hip/hip_runtime.h>
#include <math.h>

#define HW 65536
#define LAM 0.05f

struct Scal {
  double pap_re, pap_im, rq_re, rq_im, qq;
  double rs_old, al_re, al_im, beta;
  int done, apply, cnt, pad;
};

__device__ __forceinline__ float2 cadd(float2 a, float2 b){ return make_float2(a.x+b.x, a.y+b.y); }
__device__ __forceinline__ float2 csub(float2 a, float2 b){ return make_float2(a.x-b.x, a.y-b.y); }
__device__ __forceinline__ float2 cmul(float2 a, float2 b){
  return make_float2(a.x*b.x - a.y*b.y, a.x*b.y + a.y*b.x);
}
__device__ __forceinline__ float2 cmulj(float2 a, float2 b){ // conj(a)*b
  return make_float2(a.x*b.x + a.y*b.y, a.x*b.y - a.y*b.x);
}
__device__ __forceinline__ int swz(int p){ return p ^ (p>>4); }

__device__ __forceinline__ void wave_lds_sync(){
  __builtin_amdgcn_wave_barrier();
  __asm__ __volatile__("s_waitcnt lgkmcnt(0)" ::: "memory");
  __builtin_amdgcn_wave_barrier();
}

template<int S>
__device__ __forceinline__ void bfly4(float2 x0, float2 x1, float2 x2, float2 x3,
                                      float2& y0, float2& y1, float2& y2, float2& y3){
  float2 a  = cadd(x0,x2), bm = csub(x0,x2);
  float2 c  = cadd(x1,x3), d  = csub(x1,x3);
  float2 jd = make_float2(-(float)S*d.y, (float)S*d.x);
  y0 = cadd(a,c); y2 = csub(a,c); y1 = cadd(bm,jd); y3 = csub(bm,jd);
}

// in-register DFT-16, natural order in/out. W16 = e^{S*2pi*i/16}.
template<int S>
__device__ __forceinline__ void dft16(float2* a){
  const float s_ = (float)S;
  const float2 W1 = make_float2( 0.92387953251f,  s_*0.38268343236f);
  const float2 W2 = make_float2( 0.70710678119f,  s_*0.70710678119f);
  const float2 W3 = make_float2( 0.38268343236f,  s_*0.92387953251f);
  const float2 W4_ = make_float2(0.f,              s_*1.f);
  const float2 W6 = make_float2(-0.70710678119f,  s_*0.70710678119f);
  const float2 W9 = make_float2(-0.92387953251f, -s_*0.38268343236f);
  float2 t[16];
#pragma unroll
  for (int n0=0;n0<4;n0++){
    float2 y0,y1,y2,y3;
    bfly4<S>(a[n0], a[n0+4], a[n0+8], a[n0+12], y0,y1,y2,y3);
    if (n0==1){ y1=cmul(y1,W1); y2=cmul(y2,W2); y3=cmul(y3,W3); }
    if (n0==2){ y1=cmul(y1,W2); y2=cmul(y2,W4_); y3=cmul(y3,W6); }
    if (n0==3){ y1=cmul(y1,W3); y2=cmul(y2,W6); y3=cmul(y3,W9); }
    t[n0*4+0]=y0; t[n0*4+1]=y1; t[n0*4+2]=y2; t[n0*4+3]=y3;
  }
#pragma unroll
  for (int k1=0;k1<4;k1++){
    float2 y0,y1,y2,y3;
    bfly4<S>(t[0*4+k1], t[1*4+k1], t[2*4+k1], t[3*4+k1], y0,y1,y2,y3);
    a[k1+0]=y0; a[k1+4]=y1; a[k1+8]=y2; a[k1+12]=y3;
  }
}

// 256-pt FFT, two radix-16 stages, 16 lanes (l) per FFT, swizzled LDS slice.
template<int S>
__device__ void fft256_r16(float2* buf, int l){
  float2 a[16];
#pragma unroll
  for (int j=0;j<16;j++) a[j] = buf[swz(l + 16*j)];
  dft16<S>(a);
  float ang = (float)S * 6.2831853071795865f * (float)l * (1.f/256.f);
  float sn, cs; __sincosf(ang, &sn, &cs);
  float2 wstep = make_float2(cs, sn);
  float2 w = wstep;
#pragma unroll
  for (int k=1;k<16;k++){ a[k] = cmul(a[k], w); w = cmul(w, wstep); }
#pragma unroll
  for (int k=0;k<16;k++) buf[swz(16*k + l)] = a[k];
  wave_lds_sync();
#pragma unroll
  for (int j=0;j<16;j++) a[j] = buf[swz(16*l + j)];
  dft16<S>(a);
  wave_lds_sync();
#pragma unroll
  for (int k=0;k<16;k++) buf[swz(l + 16*k)] = a[k];
  wave_lds_sync();
}

// Compressed W, packed layout per b (9*HW floats):
//   WA float4[HW] = {d0,d1,d2,o01r}; WB float4[HW] = {o01i,o02r,o02i,o12r};
//   WC float [HW] = {o12i};  indexed by wb = v*256+u. Folded 1/65536 norm.
// Also inits Scal (block 0).
__global__ __launch_bounds__(256) void k_w(const float* __restrict__ mask,
                                           const float* __restrict__ tbr,
                                           const float* __restrict__ tbi,
                                           float* __restrict__ Wf,
                                           Scal* sc){
  if (blockIdx.x==0 && blockIdx.y==0 && threadIdx.x==0){
    sc->pap_re=0.0; sc->pap_im=0.0; sc->rq_re=0.0; sc->rq_im=0.0; sc->qq=0.0;
    sc->rs_old=0.0; sc->al_re=0.0; sc->al_im=0.0; sc->beta=0.0;
    sc->done=0; sc->apply=0; sc->cnt=0;
  }
  __shared__ float wtf[9][16][17];
  int tid = threadIdx.x;
  int bx = blockIdx.x;
  int b  = blockIdx.y;
  int u0 = (bx>>4)<<4, v0 = (bx&15)<<4;
  int u_l = tid>>4, v_l = tid&15;
  int pix = (u0+u_l)*256 + (v0+v_l);
  float d0=0,d1=0,d2=0, o01r=0,o01i=0, o02r=0,o02i=0, o12r=0,o12i=0;
#pragma unroll
  for (int t=0;t<12;t++){
    float m = mask[(size_t)(b*12+t)*HW + pix];
    int lb = (b*12+t)*3;
    float l0r = tbr[lb+0], l0i = tbi[lb+0];
    float l1r = tbr[lb+1], l1i = tbi[lb+1];
    float l2r = tbr[lb+2], l2i = tbi[lb+2];
    d0 += m*(l0r*l0r + l0i*l0i);
    d1 += m*(l1r*l1r + l1i*l1i);
    d2 += m*(l2r*l2r + l2i*l2i);
    o01r += m*(l0r*l1r + l0i*l1i); o01i += m*(l0r*l1i - l0i*l1r);
    o02r += m*(l0r*l2r + l0i*l2i); o02i += m*(l0r*l2i - l0i*l2r);
    o12r += m*(l1r*l2r + l1i*l2i); o12i += m*(l1r*l2i - l1i*l2r);
  }
  const float s = 1.0f/65536.0f;
  wtf[0][u_l][v_l] = d0*s;   wtf[1][u_l][v_l] = d1*s;   wtf[2][u_l][v_l] = d2*s;
  wtf[3][u_l][v_l] = o01r*s; wtf[4][u_l][v_l] = o01i*s;
  wtf[5][u_l][v_l] = o02r*s; wtf[6][u_l][v_l] = o02i*s;
  wtf[7][u_l][v_l] = o12r*s; wtf[8][u_l][v_l] = o12i*s;
  __syncthreads();
  int u_l2 = tid&15, v_l2 = tid>>4;
  float* W0 = Wf + (size_t)b*9*HW;
  float4* WA = (float4*)W0;
  float4* WB = (float4*)(W0 + (size_t)4*HW);
  float*  WC = W0 + (size_t)8*HW;
  size_t wb = (size_t)(v0+v_l2)*256 + (u0+u_l2);
  WA[wb] = make_float4(wtf[0][u_l2][v_l2], wtf[1][u_l2][v_l2],
                       wtf[2][u_l2][v_l2], wtf[3][u_l2][v_l2]);
  WB[wb] = make_float4(wtf[4][u_l2][v_l2], wtf[5][u_l2][v_l2],
                       wtf[6][u_l2][v_l2], wtf[7][u_l2][v_l2]);
  WC[wb] = wtf[8][u_l2][v_l2];
}

// Fused setup: bufA rows = row-fft( (1/256) * D * sum_t conj(L_ts) Y[b,t,c] )
// 640 threads: staging thread = (c = tid>>6, px4 = tid&63), float4 Y loads.
__global__ __launch_bounds__(640) void k_yrow(const float* __restrict__ kr,
                                              const float* __restrict__ ki,
                                              const float* __restrict__ tbr,
                                              const float* __restrict__ tbi,
                                              float2* __restrict__ bufA){
  __shared__ float2 lb[30*257];
  int tid = threadIdx.x;
  int r = blockIdx.x, b = blockIdx.y;
  {
    int c = tid>>6, px4 = tid&63;
    float ar[3][4], ai[3][4];
#pragma unroll
    for (int s=0;s<3;s++)
#pragma unroll
      for (int j=0;j<4;j++){ ar[s][j]=0.f; ai[s][j]=0.f; }
#pragma unroll
    for (int t=0;t<12;t++){
      size_t off = ((size_t)((b*12+t)*10+c))*HW + (size_t)r*256 + 4*px4;
      float4 yr4 = *(const float4*)(kr + off);
      float4 yi4 = *(const float4*)(ki + off);
      int lbi = (b*12+t)*3;
      float l0r = tbr[lbi+0], l0i = tbi[lbi+0];
      float l1r = tbr[lbi+1], l1i = tbi[lbi+1];
      float l2r = tbr[lbi+2], l2i = tbi[lbi+2];
      float yrj[4] = {yr4.x, yr4.y, yr4.z, yr4.w};
      float yij[4] = {yi4.x, yi4.y, yi4.z, yi4.w};
#pragma unroll
      for (int j=0;j<4;j++){
        float yr = yrj[j], yi = yij[j];
        ar[0][j] += l0r*yr + l0i*yi;  ai[0][j] += l0r*yi - l0i*yr;
        ar[1][j] += l1r*yr + l1i*yi;  ai[1][j] += l1r*yi - l1i*yr;
        ar[2][j] += l2r*yr + l2i*yi;  ai[2][j] += l2r*yi - l2i*yr;
      }
    }
#pragma unroll
    for (int j=0;j<4;j++){
      int px = 4*px4 + j;
      float sg = (((r ^ px) & 1) ? -1.f : 1.f) * (1.f/256.f);
      int sk = swz(px);
#pragma unroll
      for (int s=0;s<3;s++)
        lb[(c*3+s)*257 + sk] = make_float2(ar[s][j]*sg, ai[s][j]*sg);
    }
  }
  __syncthreads();
  int wv = tid>>6, lane = tid&63, g = lane>>4, l = lane&15;
  int tau = 4*wv + g;
  if (tau < 30){
    float2* lw = &lb[tau*257];
    fft256_r16<-1>(lw, l);
    float2* dst = bufA + (size_t)(b*30+tau)*HW + (size_t)r*256;
#pragma unroll
    for (int j=0;j<8;j++){
      int e = 2*(16*j + l);
      float2 e0 = lw[swz(e)], e1 = lw[swz(e+1)];
      *(float4*)(dst + e) = make_float4(e0.x,e0.y,e1.x,e1.y);
    }
  }
}

// Column pass, in-place. 8 cols/block, 384 threads (24 FFT slots).
// MODE 0: col-fft (-1). MODE 1: col-ifft(+1) + Hermitian W mix + col-fft(-1).
template<int MODE>
__global__ __launch_bounds__(384) void k_colpass(float2* __restrict__ bufA,
                                                 const float* __restrict__ Wf){
  __shared__ float2 lb[24*257];
  int tid = threadIdx.x;
  int wv = tid>>6, lane = tid&63, g = lane>>4, l = lane&15;
  int j0 = blockIdx.x*8;
  int c = blockIdx.y, b = blockIdx.z;
#pragma unroll
  for (int it=0; it<8; it++){
    int idx = it*384 + tid;
    int s = idx>>10, rem = idx&1023, u = rem>>2, cp = rem&3;
    const float2* src = bufA + (size_t)(b*30 + c*3 + s)*HW;
    float4 v = *(const float4*)(src + u*256 + j0 + 2*cp);
    lb[(s*8+2*cp  )*257 + swz(u)] = make_float2(v.x, v.y);
    lb[(s*8+2*cp+1)*257 + swz(u)] = make_float2(v.z, v.w);
  }
  __syncthreads();
  int tau = 4*wv + g;
  if (MODE==0){
    fft256_r16<-1>(&lb[tau*257], l);
  } else {
    fft256_r16<1>(&lb[tau*257], l);
    __syncthreads();
    const float* W0 = Wf + (size_t)b*9*HW;
    const float4* WA = (const float4*)W0;
    const float4* WB = (const float4*)(W0 + (size_t)4*HW);
    const float*  WC = W0 + (size_t)8*HW;
    for (int idx=tid; idx<2048; idx+=384){
      int u = idx&255, col = idx>>8;
      int su = swz(u);
      int v = j0 + col;
      float2 x0 = lb[(0*8+col)*257 + su];
      float2 x1 = lb[(1*8+col)*257 + su];
      float2 x2 = lb[(2*8+col)*257 + su];
      size_t wb = (size_t)v*256 + u;
      float4 wa = WA[wb];
      float4 wbv = WB[wb];
      float d0 = wa.x, d1 = wa.y, d2 = wa.z, o01r = wa.w;
      float o01i = wbv.x, o02r = wbv.y, o02i = wbv.z, o12r = wbv.w;
      float o12i = WC[wb];
      float2 y0, y1, y2;
      y0.x = d0*x0.x + o01r*x1.x - o01i*x1.y + o02r*x2.x - o02i*x2.y;
      y0.y = d0*x0.y + o01r*x1.y + o01i*x1.x + o02r*x2.y + o02i*x2.x;
      y1.x = o01r*x0.x + o01i*x0.y + d1*x1.x + o12r*x2.x - o12i*x2.y;
      y1.y = o01r*x0.y - o01i*x0.x + d1*x1.y + o12r*x2.y + o12i*x2.x;
      y2.x = o02r*x0.x + o02i*x0.y + o12r*x1.x + o12i*x1.y + d2*x2.x;
      y2.y = o02r*x0.y - o02i*x0.x + o12r*x1.y - o12i*x1.x + d2*x2.y;
      lb[(0*8+col)*257 + su] = y0;
      lb[(1*8+col)*257 + su] = y1;
      lb[(2*8+col)*257 + su] = y2;
    }
    __syncthreads();
    fft256_r16<-1>(&lb[tau*257], l);
  }
  __syncthreads();
#pragma unroll
  for (int it=0; it<8; it++){
    int idx = it*384 + tid;
    int s = idx>>10, rem = idx&1023, u = rem>>2, cp = rem&3;
    float2* dst = bufA + (size_t)(b*30 + c*3 + s)*HW;
    float2 e0 = lb[(s*8+2*cp  )*257 + swz(u)];
    float2 e1 = lb[(s*8+2*cp+1)*257 + swz(u)];
    *(float4*)(dst + u*256 + j0 + 2*cp) = make_float4(e0.x, e0.y, e1.x, e1.y);
  }
}

// Fused setup combine + first S*p staging (replaces k_combine + spfft#0):
// stage bufA row -> conj(S) combine + LAM*D*MO -> z=0, r=p=b, rs_old atomic
// -> S*b staging -> row-ifft -> bufA. In-place on bufA (block owns its row).
__global__ __launch_bounds__(512) void k_bsp(const float* __restrict__ sr_,
                                             const float* __restrict__ si_,
                                             const float* __restrict__ mor,
                                             const float* __restrict__ moi,
                                             float2* __restrict__ z,
                                             float2* __restrict__ rvec,
                                             float2* __restrict__ p,
                                             float2* __restrict__ bufA,
                                             Scal* sc){
  __shared__ float2 lb[30*257];
  __shared__ float2 pb[3][256];   // partial-combine then b-row buffer
  __shared__ double sd[8];
  int tid = threadIdx.x;
  int wv = tid>>6, lane = tid&63, g = lane>>4, l = lane&15;
  int r = blockIdx.x, b = blockIdx.y;
  int px = tid & 255, h = tid >> 8, sk = swz(px);
  // T14 hoist: S loads (5 coils/thread) + MO loads, issued before LDS staging
  float2 sv5[5];
#pragma unroll
  for (int k=0;k<5;k++){
    int c = h + 2*k;
    size_t so = (size_t)(b*10+c)*HW + (size_t)r*256 + px;
    sv5[k] = make_float2(sr_[so], si_[so]);
  }
  float mo_r[3], mo_i[3];
  if (h==0){
#pragma unroll
    for (int s=0;s<3;s++){
      size_t oi = (size_t)(b*3+s)*HW + (size_t)r*256 + px;
      mo_r[s] = mor[oi]; mo_i[s] = moi[oi];
    }
  }
  // stage bufA row (30 planes) into LDS
  int tau = 4*wv + g;
  if (tau < 30){
    const float2* src = bufA + (size_t)(b*30+tau)*HW + (size_t)r*256;
    float2* lw = &lb[tau*257];
#pragma unroll
    for (int j=0;j<8;j++){
      int e = 2*(16*j + l);
      float4 v = *(const float4*)(src + e);
      lw[swz(e)]   = make_float2(v.x, v.y);
      lw[swz(e+1)] = make_float2(v.z, v.w);
    }
  }
  __syncthreads();
  // conj(S) combine, two c-halves
  float2 a0={0,0}, a1={0,0}, a2={0,0};
#pragma unroll
  for (int k=0;k<5;k++){
    a0 = cadd(a0, cmulj(sv5[k], lb[((h+2*k)*3+0)*257 + sk]));
    a1 = cadd(a1, cmulj(sv5[k], lb[((h+2*k)*3+1)*257 + sk]));
    a2 = cadd(a2, cmulj(sv5[k], lb[((h+2*k)*3+2)*257 + sk]));
  }
  if (h==1){ pb[0][px]=a0; pb[1][px]=a1; pb[2][px]=a2; }
  __syncthreads();
  double dre = 0.0;
  if (h==0){
    a0 = cadd(a0, pb[0][px]);
    a1 = cadd(a1, pb[1][px]);
    a2 = cadd(a2, pb[2][px]);
    float sgl = (((r ^ px) & 1) ? -1.f : 1.f) * LAM;
    a0.x += sgl*mo_r[0]; a0.y += sgl*mo_i[0];
    a1.x += sgl*mo_r[1]; a1.y += sgl*mo_i[1];
    a2.x += sgl*mo_r[2]; a2.y += sgl*mo_i[2];
    float2 accs[3] = {a0,a1,a2};
#pragma unroll
    for (int s=0;s<3;s++){
      size_t oi = (size_t)(b*3+s)*HW + (size_t)r*256 + px;
      z[oi] = make_float2(0.f,0.f);
      rvec[oi] = accs[s]; p[oi] = accs[s];
      dre += (double)accs[s].x*accs[s].x + (double)accs[s].y*accs[s].y;
    }
    pb[0][px]=a0; pb[1][px]=a1; pb[2][px]=a2;   // b-row for S*p staging
  }
  for (int off=32; off>0; off>>=1) dre += __shfl_down(dre, off, 64);
  if (lane==0) sd[wv] = dre;
  __syncthreads();
  if (tid==0){
    double t=0;
#pragma unroll
    for (int q=0;q<8;q++) t += sd[q];
    atomicAdd(&sc->rs_old, t);
  }
  // S*p staging (all 512 threads, 5 coils each) using hoisted sv5
  {
    float2 pv0 = pb[0][px], pv1 = pb[1][px], pv2 = pb[2][px];
#pragma unroll
    for (int k=0;k<5;k++){
      int c = h + 2*k;
      lb[(c*3+0)*257 + sk] = cmul(sv5[k], pv0);
      lb[(c*3+1)*257 + sk] = cmul(sv5[k], pv1);
      lb[(c*3+2)*257 + sk] = cmul(sv5[k], pv2);
    }
  }
  __syncthreads();
  if (tau < 30){
    float2* lw = &lb[tau*257];
    fft256_r16<1>(lw, l);
    float2* dst = bufA + (size_t)(b*30+tau)*HW + (size_t)r*256;
#pragma unroll
    for (int j=0;j<8;j++){
      int e = 2*(16*j + l);
      float2 e0 = lw[swz(e)], e1 = lw[swz(e+1)];
      *(float4*)(dst + e) = make_float4(e0.x,e0.y,e1.x,e1.y);
    }
  }
}

// Fused lazy CG update (z += a*p, r -= a*Ap, p = r + beta*p, when apply)
// + S*p + row-ifft. Block = (row r, b), 512 threads. S loads hoisted.
__global__ __launch_bounds__(512) void k_spfft(float2* __restrict__ p,
                                               float2* __restrict__ rvec,
                                               float2* __restrict__ z,
                                               const float2* __restrict__ Ap,
                                               const float* __restrict__ sr_,
                                               const float* __restrict__ si_,
                                               float2* __restrict__ bufA,
                                               Scal* sc){
  __shared__ float2 lb[30*257];
  __shared__ float2 pbuf[3][256];
  int tid = threadIdx.x;
  int wv = tid>>6, lane = tid&63, g = lane>>4, l = lane&15;
  int r = blockIdx.x, b = blockIdx.y;
  int px = tid & 255, h = tid >> 8, sk = swz(px);
  // T14 hoist: S loads issued first (consumed after the sync)
  float2 sv5[5];
#pragma unroll
  for (int k=0;k<5;k++){
    int c = h + 2*k;
    size_t so = (size_t)(b*10+c)*HW + (size_t)r*256 + px;
    sv5[k] = make_float2(sr_[so], si_[so]);
  }
  int ap = sc->apply;
  float2 alpha = make_float2((float)sc->al_re, (float)sc->al_im);
  float beta = (float)sc->beta;
  // lazy CG update spread over all 512 threads (768 float2 units)
  for (int i = tid; i < 768; i += 512){
    int s = i>>8, ppx = i&255;
    size_t oi = (size_t)(b*3+s)*HW + (size_t)r*256 + ppx;
    float2 pvv = p[oi];
    if (ap){
      float2 zv = z[oi], rv = rvec[oi], apv = Ap[oi];
      zv = cadd(zv, cmul(alpha, pvv));
      rv = csub(rv, cmul(alpha, apv));
      float2 pn = make_float2(rv.x + beta*pvv.x, rv.y + beta*pvv.y);
      z[oi] = zv; rvec[oi] = rv; p[oi] = pn;
      pvv = pn;
    }
    pbuf[s][ppx] = pvv;
  }
  __syncthreads();
  // S*p staging: all threads, 5 coils each, using hoisted sv5
  {
    float2 pv0 = pbuf[0][px], pv1 = pbuf[1][px], pv2 = pbuf[2][px];
#pragma unroll
    for (int k=0;k<5;k++){
      int c = h + 2*k;
      lb[(c*3+0)*257 + sk] = cmul(sv5[k], pv0);
      lb[(c*3+1)*257 + sk] = cmul(sv5[k], pv1);
      lb[(c*3+2)*257 + sk] = cmul(sv5[k], pv2);
    }
  }
  __syncthreads();
  int tau = 4*wv + g;
  if (tau < 30){
    float2* lw = &lb[tau*257];
    fft256_r16<1>(lw, l);
    float2* dst = bufA + (size_t)(b*30+tau)*HW + (size_t)r*256;
#pragma unroll
    for (int j=0;j<8;j++){
      int e = 2*(16*j + l);
      float2 e0 = lw[swz(e)], e1 = lw[swz(e+1)];
      *(float4*)(dst + e) = make_float4(e0.x,e0.y,e1.x,e1.y);
    }
  }
}

// Fused row-fft + conj(S) combine + LAM*p + dot accumulation
// (pap=<p,Ap>, rq=<r,Ap>, qq=<Ap,Ap>); last block advances CG scalars.
// S and p/r loads hoisted to kernel top (T14).
__global__ __launch_bounds__(512) void k_rowcomb(const float2* __restrict__ bufA,
                                                 const float* __restrict__ sr_,
                                                 const float* __restrict__ si_,
                                                 const float2* __restrict__ pvec,
                                                 const float2* __restrict__ rvec,
                                                 float2* __restrict__ Ap,
                                                 Scal* sc){
  __shared__ float2 lb[30*257];
  __shared__ float2 part[3][256];
  __shared__ double sd[5][4];
  int tid = threadIdx.x;
  int wv = tid>>6, lane = tid&63, g = lane>>4, l = lane&15;
  int r = blockIdx.x, b = blockIdx.y;
  int px = tid & 255, h = tid >> 8, sk = swz(px);
  // T14 hoist: S (all threads) + p/r (low half) loads issued before staging/FFT
  float2 sv5[5];
#pragma unroll
  for (int k=0;k<5;k++){
    int c = h + 2*k;
    size_t so = (size_t)(b*10+c)*HW + (size_t)r*256 + px;
    sv5[k] = make_float2(sr_[so], si_[so]);
  }
  float2 av3[3], rv3[3];
  if (h==0){
#pragma unroll
    for (int s=0;s<3;s++){
      size_t oi = (size_t)(b*3+s)*HW + (size_t)r*256 + px;
      av3[s] = pvec[oi]; rv3[s] = rvec[oi];
    }
  }
  int tau = 4*wv + g;
  if (tau < 30){
    const float2* src = bufA + (size_t)(b*30+tau)*HW + (size_t)r*256;
    float2* lw = &lb[tau*257];
#pragma unroll
    for (int j=0;j<8;j++){
      int e = 2*(16*j + l);
      float4 v = *(const float4*)(src + e);
      lw[swz(e)]   = make_float2(v.x, v.y);
      lw[swz(e+1)] = make_float2(v.z, v.w);
    }
    wave_lds_sync();
    fft256_r16<-1>(lw, l);
  }
  __syncthreads();
  float2 a0={0,0}, a1={0,0}, a2={0,0};
#pragma unroll
  for (int k=0;k<5;k++){
    a0 = cadd(a0, cmulj(sv5[k], lb[((h+2*k)*3+0)*257 + sk]));
    a1 = cadd(a1, cmulj(sv5[k], lb[((h+2*k)*3+1)*257 + sk]));
    a2 = cadd(a2, cmulj(sv5[k], lb[((h+2*k)*3+2)*257 + sk]));
  }
  if (h==1){ part[0][px]=a0; part[1][px]=a1; part[2][px]=a2; }
  __syncthreads();
  double d0=0.0, d1=0.0, d2=0.0, d3=0.0, d4=0.0;
  if (tid < 256){
    a0 = cadd(a0, part[0][px]);
    a1 = cadd(a1, part[1][px]);
    a2 = cadd(a2, part[2][px]);
    float2 accs[3] = {a0,a1,a2};
#pragma unroll
    for (int s=0;s<3;s++){
      size_t oi = (size_t)(b*3+s)*HW + (size_t)r*256 + px;
      float2 acc = accs[s];
      float2 av = av3[s];
      float2 rv = rv3[s];
      acc.x += LAM*av.x; acc.y += LAM*av.y;
      Ap[oi] = acc;
      d0 += (double)av.x*acc.x + (double)av.y*acc.y;   // pap
      d1 += (double)av.x*acc.y - (double)av.y*acc.x;
      d2 += (double)rv.x*acc.x + (double)rv.y*acc.y;   // rq
      d3 += (double)rv.x*acc.y - (double)rv.y*acc.x;
      d4 += (double)acc.x*acc.x + (double)acc.y*acc.y; // qq
    }
  }
  for (int off=32; off>0; off>>=1){
    d0 += __shfl_down(d0, off, 64);
    d1 += __shfl_down(d1, off, 64);
    d2 += __shfl_down(d2, off, 64);
    d3 += __shfl_down(d3, off, 64);
    d4 += __shfl_down(d4, off, 64);
  }
  if (lane==0 && wv<4){ sd[0][wv]=d0; sd[1][wv]=d1; sd[2][wv]=d2; sd[3][wv]=d3; sd[4][wv]=d4; }
  __syncthreads();
  if (tid==0){
    double t0=0,t1=0,t2=0,t3=0,t4=0;
#pragma unroll
    for (int q=0;q<4;q++){ t0+=sd[0][q]; t1+=sd[1][q]; t2+=sd[2][q]; t3+=sd[3][q]; t4+=sd[4][q]; }
    atomicAdd(&sc->pap_re, t0); atomicAdd(&sc->pap_im, t1);
    atomicAdd(&sc->rq_re,  t2); atomicAdd(&sc->rq_im,  t3);
    atomicAdd(&sc->qq,     t4);
    int total = (int)(gridDim.x*gridDim.y);
    int prev = atomicAdd(&sc->cnt, 1);
    if (prev == total-1){
      sc->cnt = 0;
      if (!sc->done){
        double pr = sc->pap_re + 1e-20, pi = sc->pap_im;
        double den = pr*pr + pi*pi;
        double rs = sc->rs_old;
        double alr =  rs*pr/den, ali = -rs*pi/den;
        double rs_new = rs - 2.0*(alr*sc->rq_re - ali*sc->rq_im)
                           + (alr*alr + ali*ali)*sc->qq;
        sc->al_re = alr; sc->al_im = ali;
        sc->beta = rs_new/(rs + 1e-20);
        sc->rs_old = rs_new;
        sc->apply = 1;
        if (fabs(rs_new) < 1e-10) sc->done = 1;
      } else {
        sc->apply = 0;
      }
      sc->pap_re=0.0; sc->pap_im=0.0; sc->rq_re=0.0; sc->rq_im=0.0; sc->qq=0.0;
    }
  }
}

// Output: apply pending z += alpha*p, un-tilde (D), interleave re/im.
__global__ __launch_bounds__(256) void k_out(const float2* __restrict__ z,
                                             const float2* __restrict__ p,
                                             const Scal* sc,
                                             float* __restrict__ out){
  int i = blockIdx.x*256 + threadIdx.x;
  int pix = i & (HW-1);
  float sgn = (((pix>>8)^pix)&1) ? -1.f : 1.f;
  float2 zv = z[i];
  if (sc->apply){
    float2 alpha = make_float2((float)sc->al_re, (float)sc->al_im);
    zv = cadd(zv, cmul(alpha, p[i]));
  }
  out[2*i]   = sgn*zv.x;
  out[2*i+1] = sgn*zv.y;
}

extern "C" void kernel_launch(void* const* d_in, const int* in_sizes, int n_in,
                              void* d_out, int out_size, void* d_ws, size_t ws_size,
                              hipStream_t stream){
  const float* kr   = (const float*)d_in[0];
  const float* ki   = (const float*)d_in[1];
  const float* mor  = (const float*)d_in[2];
  const float* moi  = (const float*)d_in[3];
  const float* sr   = (const float*)d_in[4];
  const float* si   = (const float*)d_in[5];
  const float* tbr  = (const float*)d_in[6];
  const float* tbi  = (const float*)d_in[7];
  const float* mask = (const float*)d_in[8];
  float* out = (float*)d_out;

  float2* ws   = (float2*)d_ws;
  float2* bufA = ws;                       // 60*HW float2
  float*  Wf   = (float*)(ws + 3932160);   // 18*HW floats (9*HW per b, packed)
  float2* z    = ws + 4521984;             // 6*HW each
  float2* r    = ws + 4915200;
  float2* p    = ws + 5308416;
  float2* Ap   = ws + 5701632;
  Scal*   sc   = (Scal*)(ws + 6094848);

  k_w<<<dim3(256,2),dim3(256),0,stream>>>(mask, tbr, tbi, Wf, sc);
  k_yrow<<<dim3(256,2),dim3(640),0,stream>>>(kr, ki, tbr, tbi, bufA);
  k_colpass<0><<<dim3(32,10,2),dim3(384),0,stream>>>(bufA, Wf);
  k_bsp<<<dim3(256,2),dim3(512),0,stream>>>(sr, si, mor, moi, z, r, p,
                                            bufA, sc);
  for (int it=0; it<6; ++it){
    if (it > 0)
      k_spfft<<<dim3(256,2),dim3(512),0,stream>>>(p, r, z, Ap, sr, si, bufA, sc);
    k_colpass<1><<<dim3(32,10,2),dim3(384),0,stream>>>(bufA, Wf);
    k_rowcomb<<<dim3(256,2),dim3(512),0,stream>>>(bufA, sr, si, p, r, Ap, sc);
  }
  k_out<<<dim3(1536),dim3(256),0,stream>>>(z, p, sc, out);
}